// Round 1
// baseline (1364.066 us; speedup 1.0000x reference)
//
#include <hip/hip_runtime.h>

// Node2Prop2: out[g] = sum_{i: batch[i]==g} ( softplus(x[i]@W1 + b1) - ln2 ) @ W2
// x: (N,128) f32, W1: (128,128) f32, b1: (128,) f32, W2: (128,1) f32,
// batch: (N,) i32 sorted, out: (10000,) f32.
//
// Strategy: bf16 MFMA (16x16x32) for x@W1 (memory-bound at ~165us HBM floor;
// fp32 vector ALU would be ~417us compute-bound). W1^T in LDS as bf16 with
// padded k-stride (136) -> bank-balanced ds_read_b128 B-frags. Fused epilogue:
// softplus + dot(W2) + cross-lane reduce + sorted-key segmented atomicAdd.

typedef float f32x4 __attribute__((ext_vector_type(4)));
typedef __bf16 bf16x8 __attribute__((ext_vector_type(8)));

#define LDSP 136  // padded k-stride (bf16 elems): 272 B rows -> 2-way max bank alias (free)

__global__ void zero_kernel(float* __restrict__ p, int m) {
  int i = blockIdx.x * 256 + threadIdx.x;
  if (i < m) p[i] = 0.0f;
}

__global__ __launch_bounds__(256) void node2prop_kernel(
    const float* __restrict__ x, const float* __restrict__ W1,
    const float* __restrict__ b1, const float* __restrict__ W2,
    const int* __restrict__ batch, float* __restrict__ out,
    int n, int ntiles)
{
  __shared__ __bf16 w1t[128 * LDSP];   // W1^T: [n][k], 34.8 KB
  __shared__ float node_out[64];

  const int tid = threadIdx.x;

  // Stage W1 -> LDS transposed as bf16 (once per block; W1 is 64KB, L2/L3-hot)
  for (int idx = tid; idx < 128 * 128; idx += 256) {
    int k = idx >> 7, nn = idx & 127;      // W1[k][nn] row-major
    w1t[nn * LDSP + k] = (__bf16)W1[idx];
  }

  const int lane = tid & 63;
  const int wv   = tid >> 6;    // wave 0..3
  const int l15  = lane & 15;
  const int quad = lane >> 4;

  // Per-lane bias / W2 for output columns n = t*16 + l15
  float b1v[8], w2v[8];
#pragma unroll
  for (int t = 0; t < 8; ++t) {
    b1v[t] = b1[t * 16 + l15];
    w2v[t] = W2[t * 16 + l15];
  }

  __syncthreads();

  const float LN2 = 0.69314718055994531f;

  for (int tile = blockIdx.x; tile < ntiles; tile += gridDim.x) {
    // This wave's 16 node rows: rowbase .. rowbase+15
    long rowbase = (long)tile * 64 + wv * 16;
    long arow = rowbase + l15;             // A-frag: m = lane&15
    if (arow >= n) arow = (long)n - 1;     // clamp (tail; val zeroed in scatter)
    const float* xrow = x + arow * 128 + quad * 8;   // k = quad*8 + j

    f32x4 acc[8];
#pragma unroll
    for (int t = 0; t < 8; ++t) acc[t] = (f32x4){0.f, 0.f, 0.f, 0.f};

#pragma unroll
    for (int ks = 0; ks < 4; ++ks) {       // K = 128 in 4 steps of 32
      float4 a0 = *(const float4*)(xrow + ks * 32);
      float4 a1 = *(const float4*)(xrow + ks * 32 + 4);
      bf16x8 a;
      a[0] = (__bf16)a0.x; a[1] = (__bf16)a0.y; a[2] = (__bf16)a0.z; a[3] = (__bf16)a0.w;
      a[4] = (__bf16)a1.x; a[5] = (__bf16)a1.y; a[6] = (__bf16)a1.z; a[7] = (__bf16)a1.w;
      const __bf16* bbase = &w1t[l15 * LDSP + ks * 32 + quad * 8];
#pragma unroll
      for (int t = 0; t < 8; ++t) {        // 8 n-tiles of 16 cols
        bf16x8 b = *(const bf16x8*)(bbase + t * 16 * LDSP);  // ds_read_b128
        acc[t] = __builtin_amdgcn_mfma_f32_16x16x32_bf16(a, b, acc[t], 0, 0, 0);
      }
    }

    // Epilogue: z -> softplus(z+b1)-ln2, dot W2.
    // C/D layout: col = lane&15 (+16t), row m = quad*4 + r (verified m89/m91).
    float s[4] = {0.f, 0.f, 0.f, 0.f};
#pragma unroll
    for (int t = 0; t < 8; ++t) {
#pragma unroll
      for (int r = 0; r < 4; ++r) {
        float z = acc[t][r] + b1v[t];
        float h = fmaxf(z, 0.f) + __logf(1.f + __expf(-fabsf(z))) - LN2;
        s[r] += h * w2v[t];
      }
    }
    // Reduce over the 16 lanes sharing the same quad (same rows, cols l15+16t)
#pragma unroll
    for (int off = 1; off < 16; off <<= 1) {
#pragma unroll
      for (int r = 0; r < 4; ++r) s[r] += __shfl_xor(s[r], off, 64);
    }
    if (l15 == 0) {
#pragma unroll
      for (int r = 0; r < 4; ++r) node_out[wv * 16 + quad * 4 + r] = s[r];
    }
    __syncthreads();

    // Wave 0: segmented reduce (batch sorted) over the 64-node tile + atomicAdd
    if (tid < 64) {
      long node = (long)tile * 64 + tid;
      float val; int bid;
      if (node < n) { val = node_out[tid]; bid = batch[node]; }
      else          { val = 0.f;           bid = batch[n - 1]; }
      // suffix segmented-sum over sorted keys within the wave
#pragma unroll
      for (int off = 1; off < 64; off <<= 1) {
        int   obid = __shfl_down(bid, off, 64);
        float oval = __shfl_down(val, off, 64);
        if (tid + off < 64 && obid == bid) val += oval;
      }
      int pbid = __shfl_up(bid, 1, 64);
      if (tid == 0 || pbid != bid) atomicAdd(&out[bid], val);
    }
    __syncthreads();  // node_out consumed before next iteration overwrites
  }
}

extern "C" void kernel_launch(void* const* d_in, const int* in_sizes, int n_in,
                              void* d_out, int out_size, void* d_ws, size_t ws_size,
                              hipStream_t stream) {
  const float* x     = (const float*)d_in[0];
  const float* W1    = (const float*)d_in[1];
  const float* b1    = (const float*)d_in[2];
  const float* W2    = (const float*)d_in[3];
  const int*   batch = (const int*)d_in[4];
  float* out = (float*)d_out;

  const int n = in_sizes[4];               // N_NODES
  const int ntiles = (n + 63) / 64;

  // Harness re-poisons d_out with 0xAA before every timed launch: zero it.
  zero_kernel<<<(out_size + 255) / 256, 256, 0, stream>>>(out, out_size);

  int blocks = ntiles < 4096 ? ntiles : 4096;
  node2prop_kernel<<<blocks, 256, 0, stream>>>(x, W1, b1, W2, batch, out, n, ntiles);
}